// Round 9
// baseline (7919.868 us; speedup 1.0000x reference)
//
#include <hip/hip_runtime.h>
#include <hip/hip_bf16.h>

// Encoder: 2-layer LSTM, B=64 T=256 E=512 H=1024.
// f32 device buffers; bf16 internal MFMA compute, f32 accum, f32 c-state.
// Out: outputs[64][256][1024] | h_n[2][64][1024] | c_n[2][64][1024]  (f32)
//
// Recurrence: persistent chunk kernels (64 steps/launch), grid=64 blocks
// (always co-resident on 256 CUs), Wh held in registers, K-split across
// 4 waves + LDS reduce, manual device-scope grid barrier per step
// (bounded spin: worst case proceeds after ~50 ms instead of hanging).

typedef short bf16x8 __attribute__((ext_vector_type(8)));
typedef float f32x4 __attribute__((ext_vector_type(4)));

__device__ __forceinline__ float bf2f(ushort u) {
  union { unsigned int i; float f; } v; v.i = ((unsigned int)u) << 16; return v.f;
}
__device__ __forceinline__ ushort f2bf(float f) {
  union { float f; unsigned int i; } v; v.f = f;
  unsigned int r = v.i + 0x7fffu + ((v.i >> 16) & 1u);
  return (ushort)(r >> 16);
}

// ---------------- transpose+convert: W f32 [K][4096] -> WT bf16 [4096][K] ------
__global__ __launch_bounds__(256) void transpose_cvt(const float* __restrict__ W,
                                                     ushort* __restrict__ WT, int K) {
  __shared__ ushort t[64][65];
  int bn = blockIdx.x * 64;
  int bk = blockIdx.y * 64;
  for (int s = threadIdx.x; s < 4096; s += 256) {
    int kl = s >> 6, nl = s & 63;
    t[kl][nl] = f2bf(W[(size_t)(bk + kl) * 4096 + bn + nl]);
  }
  __syncthreads();
  for (int s = threadIdx.x; s < 4096; s += 256) {
    int nl = s >> 6, kl = s & 63;
    WT[(size_t)(bn + nl) * K + bk + kl] = t[kl][nl];
  }
}

// ---------------- G_chunk = A @ W + b (4096 rows = 64 steps x 64 batch) --------
__device__ __forceinline__ int swz(int row, int kElem) {
  int byte = row * 128 + kElem * 2;
  return byte ^ ((row & 7) << 4);
}

template <bool AF32>
__global__ __launch_bounds__(256) void gemm_xw(const void* __restrict__ Av,
                                               const int* __restrict__ gather, int tbase,
                                               const ushort* __restrict__ WT,
                                               const float* __restrict__ bias,
                                               ushort* __restrict__ G, int K) {
  int bx = blockIdx.x & 31;
  int by = blockIdx.x >> 5;
  int tid = threadIdx.x;
  int w = tid >> 6, l = tid & 63;
  int wr = w >> 1, wc = w & 1;
  int lr = l & 15, lk = (l >> 4) * 8;

  __shared__ alignas(16) char At[128 * 64 * 2];
  __shared__ alignas(16) char Bt[128 * 64 * 2];

  int srow = tid >> 3;
  int skof = (tid & 7) * 8;

  size_t aoff[4];
  const ushort* brow[4];
#pragma unroll
  for (int c2 = 0; c2 < 4; ++c2) {
    int m = by * 128 + c2 * 32 + srow;
    long idx = gather ? (long)gather[(m & 63) * 256 + tbase + (m >> 6)] : (long)m;
    aoff[c2] = (size_t)idx * K + skof;
    int n = bx * 128 + c2 * 32 + srow;
    brow[c2] = WT + (size_t)n * K + skof;
  }

  f32x4 zero = {0.f, 0.f, 0.f, 0.f};
  f32x4 acc[4][4];
#pragma unroll
  for (int i = 0; i < 4; ++i)
#pragma unroll
    for (int j = 0; j < 4; ++j) acc[i][j] = zero;

  for (int kc = 0; kc < K; kc += 64) {
    bf16x8 ar[4], br[4];
#pragma unroll
    for (int c2 = 0; c2 < 4; ++c2) {
      if (AF32) {
        const float* p = (const float*)Av + aoff[c2] + kc;
        f32x4 x0 = *(const f32x4*)p;
        f32x4 x1 = *(const f32x4*)(p + 4);
#pragma unroll
        for (int j = 0; j < 4; ++j) {
          ar[c2][j] = (short)f2bf(x0[j]);
          ar[c2][4 + j] = (short)f2bf(x1[j]);
        }
      } else {
        ar[c2] = *(const bf16x8*)((const ushort*)Av + aoff[c2] + kc);
      }
      br[c2] = *(const bf16x8*)(brow[c2] + kc);
    }
    __syncthreads();
#pragma unroll
    for (int c2 = 0; c2 < 4; ++c2) {
      *(bf16x8*)(At + swz(c2 * 32 + srow, skof)) = ar[c2];
      *(bf16x8*)(Bt + swz(c2 * 32 + srow, skof)) = br[c2];
    }
    __syncthreads();
#pragma unroll
    for (int ks = 0; ks < 2; ++ks) {
      bf16x8 af[4], bfr[4];
#pragma unroll
      for (int mt = 0; mt < 4; ++mt)
        af[mt] = *(const bf16x8*)(At + swz(wr * 64 + mt * 16 + lr, ks * 32 + lk));
#pragma unroll
      for (int nt = 0; nt < 4; ++nt)
        bfr[nt] = *(const bf16x8*)(Bt + swz(wc * 64 + nt * 16 + lr, ks * 32 + lk));
#pragma unroll
      for (int mt = 0; mt < 4; ++mt)
#pragma unroll
        for (int nt = 0; nt < 4; ++nt)
          acc[mt][nt] = __builtin_amdgcn_mfma_f32_16x16x32_bf16(af[mt], bfr[nt], acc[mt][nt], 0, 0, 0);
    }
  }

#pragma unroll
  for (int mt = 0; mt < 4; ++mt) {
#pragma unroll
    for (int nt = 0; nt < 4; ++nt) {
      int ncol = bx * 128 + wc * 64 + nt * 16 + lr;
      float bv = bias[ncol];
#pragma unroll
      for (int j = 0; j < 4; ++j) {
        int r = by * 128 + wr * 64 + mt * 16 + (l >> 4) * 4 + j;
        G[(size_t)r * 4096 + ncol] = f2bf(acc[mt][nt][j] + bv);
      }
    }
  }
}

// ---------------- persistent 64-step recurrence chunk ---------------------------
// grid 64 (ch-tiles of 16), block 256 (4 waves). Wave w: K-quarter [256w,256w+256)
// for ALL 4 m-tiles x 4 gates; Wh slice in regs (128 VGPR). LDS 4-way reduce
// lands m-tile w in wave w (thread then holds i,f,n,o for its (row,ch) cells).
// Manual grid barrier (device-scope atomics, bounded spin) between steps.
template <int LAYER>
__global__ __launch_bounds__(256) void lstm_chunk(
    const ushort* __restrict__ WhT,   // [4096][1024]
    const ushort* __restrict__ G,     // chunk [64 steps][64 batch][4096]
    ushort* __restrict__ X1,          // [256][64][1024] (layer0 h io)
    ushort* __restrict__ hA,
    ushort* __restrict__ hB,
    const ushort* __restrict__ hzero,
    float* __restrict__ cbuf,         // [64][1024] f32
    float* __restrict__ outF,         // d_out base (layer1, masked)
    const int* __restrict__ lens,
    int tbase,
    int* __restrict__ cnt) {          // [64] pre-zeroed
  const int bx = blockIdx.x;
  const int tid = threadIdx.x;
  const int w = tid >> 6;
  const int l = tid & 63;
  const int lr = l & 15;
  const int lq = l >> 4;              // 0..3

  __shared__ f32x4 red[4][4][4][64];  // [kwave][m][g][lane] = 64 KB

  // Wh slice -> registers: wreg[g][kk] covers k = w*256 + kk*32 + lq*8 .. +8
  bf16x8 wreg[4][8];
  {
    const ushort* wb = WhT + (size_t)(bx * 16 + lr) * 1024 + w * 256 + lq * 8;
#pragma unroll
    for (int g = 0; g < 4; ++g)
#pragma unroll
      for (int kk = 0; kk < 8; ++kk)
        wreg[g][kk] = *(const bf16x8*)(wb + (size_t)g * 1048576 + kk * 32);
  }

  const int ch = bx * 16 + lr;
  const int rbase = w * 16 + lq * 4;
  float c_[4];
  int len_[4];
#pragma unroll
  for (int j = 0; j < 4; ++j) {
    c_[j] = cbuf[(rbase + j) * 1024 + ch];
    len_[j] = (LAYER == 1) ? lens[rbase + j] : 0;
  }

  for (int s = 0; s < 64; ++s) {
    const int t = tbase + s;
    const ushort* hp;
    ushort* hn;
    if (LAYER == 0) {
      hp = (t == 0) ? hzero : X1 + (size_t)(t - 1) * 65536;
      hn = X1 + (size_t)t * 65536;
    } else {
      hp = (t & 1) ? hB : hA;
      hn = (t & 1) ? hA : hB;
    }

    f32x4 acc[4][4];
#pragma unroll
    for (int m = 0; m < 4; ++m)
#pragma unroll
      for (int g = 0; g < 4; ++g)
        acc[m][g] = (f32x4){0.f, 0.f, 0.f, 0.f};

#pragma unroll
    for (int kk = 0; kk < 8; ++kk) {
      bf16x8 a[4];
#pragma unroll
      for (int m = 0; m < 4; ++m)
        a[m] = *(const bf16x8*)(hp + (size_t)(m * 16 + lr) * 1024 + w * 256 + kk * 32 + lq * 8);
#pragma unroll
      for (int m = 0; m < 4; ++m)
#pragma unroll
        for (int g = 0; g < 4; ++g)
          acc[m][g] = __builtin_amdgcn_mfma_f32_16x16x32_bf16(a[m], wreg[g][kk], acc[m][g], 0, 0, 0);
    }

    // 4-way K reduce: wave w finalizes m-tile w
#pragma unroll
    for (int m = 0; m < 4; ++m)
#pragma unroll
      for (int g = 0; g < 4; ++g)
        red[w][m][g][l] = acc[m][g];
    __syncthreads();

    f32x4 sg[4];
#pragma unroll
    for (int g = 0; g < 4; ++g)
      sg[g] = red[0][w][g][l] + red[1][w][g][l] + red[2][w][g][l] + red[3][w][g][l];

#pragma unroll
    for (int j = 0; j < 4; ++j) {
      const int rr = rbase + j;
      const ushort* grow = G + ((size_t)(s * 64 + rr)) * 4096 + ch;
      float gi = sg[0][j] + bf2f(grow[0]);
      float gf = sg[1][j] + bf2f(grow[1024]);
      float gn = sg[2][j] + bf2f(grow[2048]);
      float go = sg[3][j] + bf2f(grow[3072]);
      float i_ = 1.f / (1.f + expf(-gi));
      float f_ = 1.f / (1.f + expf(-gf));
      float n_ = tanhf(gn);
      float o_ = 1.f / (1.f + expf(-go));
      float cn = f_ * c_[j] + i_ * n_;
      c_[j] = cn;
      float hv = o_ * tanhf(cn);
      hn[rr * 1024 + ch] = f2bf(hv);
      if (LAYER == 1)
        outF[(size_t)rr * 262144 + (size_t)t * 1024 + ch] = (t < len_[j]) ? hv : 0.f;
    }

    if (s != 63) {
      // grid barrier: release own h-slice, wait for all 64 blocks, acquire.
      __syncthreads();                          // all threads' stores issued
      if (tid == 0) {
        __threadfence();                        // device-scope release
        __hip_atomic_fetch_add(&cnt[s], 1, __ATOMIC_RELEASE, __HIP_MEMORY_SCOPE_AGENT);
        int guard = 1 << 20;                    // bounded spin (~50 ms max)
        while (__hip_atomic_load(&cnt[s], __ATOMIC_RELAXED, __HIP_MEMORY_SCOPE_AGENT) < 64 &&
               --guard)
          __builtin_amdgcn_s_sleep(2);
      }
      __syncthreads();
      __threadfence();                          // acquire: drop stale cached h
    }
  }

#pragma unroll
  for (int j = 0; j < 4; ++j)
    cbuf[(rbase + j) * 1024 + ch] = c_[j];
}

__global__ __launch_bounds__(256) void zero_mem(uint* __restrict__ p, int n) {
  int i = blockIdx.x * 256 + threadIdx.x;
  int stride = gridDim.x * 256;
  for (; i < n; i += stride) p[i] = 0u;
}

__global__ __launch_bounds__(256) void write_states(const ushort* __restrict__ h,
                                                    const float* __restrict__ c,
                                                    float* __restrict__ oh,
                                                    float* __restrict__ oc) {
  int i = blockIdx.x * 256 + threadIdx.x;
  oh[i] = bf2f(h[i]);
  oc[i] = c[i];
}

extern "C" void kernel_launch(void* const* d_in, const int* in_sizes, int n_in,
                              void* d_out, int out_size, void* d_ws, size_t ws_size,
                              hipStream_t stream) {
  (void)in_sizes; (void)n_in; (void)out_size; (void)ws_size;
  const int* src    = (const int*)d_in[0];
  const int* lens   = (const int*)d_in[1];
  const float* emb  = (const float*)d_in[2];
  const float* Wx0  = (const float*)d_in[3];
  const float* Wh0  = (const float*)d_in[4];
  const float* b0   = (const float*)d_in[5];
  const float* Wx1  = (const float*)d_in[6];
  const float* Wh1  = (const float*)d_in[7];
  const float* b1   = (const float*)d_in[8];
  float* out = (float*)d_out;

  char* ws = (char*)d_ws;
  ushort* Wx0T  = (ushort*)(ws + 0);          // bf16 [4096][512]
  ushort* Wh0T  = (ushort*)(ws + 4194304);    // bf16 [4096][1024]
  ushort* Wx1T  = (ushort*)(ws + 12582912);   // bf16 [4096][1024]
  ushort* Wh1T  = (ushort*)(ws + 20971520);   // bf16 [4096][1024]
  ushort* G     = (ushort*)(ws + 29360128);   // bf16 [4096][4096] (64-step chunk)
  ushort* X1    = (ushort*)(ws + 62914560);   // bf16 [256][64][1024]
  // contiguous zero region: hA | cbuf | hzero | cnt
  ushort* hA    = (ushort*)(ws + 96468992);   // bf16 [64][1024]   (131072 B)
  float*  cbuf  = (float*) (ws + 96600064);   // f32  [64][1024]   (262144 B)
  ushort* hzero = (ushort*)(ws + 96862208);   // bf16 [64][1024]   (131072 B)
  int*    cnt   = (int*)   (ws + 96993280);   // int  [8][64]      (2048 B)
  ushort* hB    = (ushort*)(ws + 96995328);   // bf16 [64][1024]   (131072 B)

  transpose_cvt<<<dim3(64, 8),  256, 0, stream>>>(Wx0, Wx0T, 512);
  transpose_cvt<<<dim3(64, 16), 256, 0, stream>>>(Wh0, Wh0T, 1024);
  transpose_cvt<<<dim3(64, 16), 256, 0, stream>>>(Wx1, Wx1T, 1024);
  transpose_cvt<<<dim3(64, 16), 256, 0, stream>>>(Wh1, Wh1T, 1024);

  // zero hA + cbuf + hzero + cnt (contiguous, 526336 B)
  zero_mem<<<128, 256, 0, stream>>>((uint*)hA, 526336 / 4);

  // ---- layer 0
  for (int c = 0; c < 4; ++c) {
    gemm_xw<true><<<1024, 256, 0, stream>>>(emb, src, c * 64, Wx0T, b0, G, 512);
    lstm_chunk<0><<<64, 256, 0, stream>>>(Wh0T, G, X1, hA, hB, hzero, cbuf,
                                          out, lens, c * 64, cnt + c * 64);
  }
  write_states<<<256, 256, 0, stream>>>(X1 + (size_t)255 * 65536, cbuf,
                                        out + 16777216, out + 16908288);

  // re-zero hA + cbuf (contiguous, 393216 B)
  zero_mem<<<128, 256, 0, stream>>>((uint*)hA, 393216 / 4);

  // ---- layer 1
  for (int c = 0; c < 4; ++c) {
    gemm_xw<false><<<1024, 256, 0, stream>>>(X1 + (size_t)c * 4194304, nullptr, 0,
                                             Wx1T, b1, G, 1024);
    lstm_chunk<1><<<64, 256, 0, stream>>>(Wh1T, G, X1, hA, hB, hzero, cbuf,
                                          out, lens, c * 64, cnt + 256 + c * 64);
  }
  // t=255 wrote buf[(255&1)^1] = hA
  write_states<<<256, 256, 0, stream>>>(hA, cbuf,
                                        out + 16777216 + 65536, out + 16908288 + 65536);
}